// Round 6
// baseline (443.593 us; speedup 1.0000x reference)
//
#include <hip/hip_runtime.h>
#include <hip/hip_bf16.h>

#define BB_ 8
#define NN_ 8192
#define SS_ 2048
#define NS 32
#define C1 64
#define C2 64
#define C3 128
#define RAD2 0.04f
#define BN_EPS 1e-5f
#define M_TOT (BB_*SS_*NS)   // 524288
#define INV_M (1.0f/524288.0f)
#define YSTR 34              // LDS row stride (dwords): conflict-free frag reads

typedef __attribute__((ext_vector_type(8))) short bf16x8;
typedef __attribute__((ext_vector_type(4))) float f32x4;

// ws float offsets
#define FBF_OFF 0          // feat bf16 [M_TOT][8] = 2,097,152 floats (8 MB)
#define WPK_OFF 2097152    // packed weight frags: 1792 uint4
#define ST_OFF  2104320    // 4 x 512 split stat buffers: gram[27](buf0) | sum2@64 sq2@128 | sum3@192 sq3@320
#define GMM_OFF 2106368    // float per (group, o3): 16384*128 = 2,097,152 floats (8 MB)

__device__ inline unsigned pkbf(float a, float b) {
    __hip_bfloat162 h = __float22bfloat162_rn(make_float2(a, b));
    unsigned r; __builtin_memcpy(&r, &h, 4); return r;
}
__device__ inline bf16x8 asfrag(uint4 v) { bf16x8 r; __builtin_memcpy(&r, &v, 16); return r; }
__device__ inline float bflo(unsigned u) { unsigned x = u << 16; float f; __builtin_memcpy(&f, &x, 4); return f; }
__device__ inline float bfhi(unsigned u) { unsigned x = u & 0xffff0000u; float f; __builtin_memcpy(&f, &x, 4); return f; }

__device__ inline void fin1_ch(const float* __restrict__ st, const float* __restrict__ W1,
                               const float* __restrict__ g, const float* __restrict__ bb,
                               int o, float* __restrict__ al, float* __restrict__ cl) {
    float w[6];
    #pragma unroll
    for (int i = 0; i < 6; ++i) w[i] = W1[o * 6 + i];
    float ms = 0.f;
    #pragma unroll
    for (int i = 0; i < 6; ++i) ms = fmaf(w[i], st[i], ms);
    float m = ms * INV_M;
    float e2 = 0.f;
    #pragma unroll
    for (int ci = 0; ci < 6; ++ci)
        #pragma unroll
        for (int d = 0; d < 6; ++d) {
            int lo = ci < d ? ci : d, hi = ci < d ? d : ci;
            int idx = 6 + lo * 6 - lo * (lo + 1) / 2 + hi;
            e2 = fmaf(w[ci] * w[d], st[idx], e2);
        }
    float var = e2 * INV_M - m * m;
    float ai = g[o] * (1.0f / sqrtf(var + BN_EPS));
    al[o] = ai;
    cl[o] = bb[o] - m * ai;
}

// sums the 4 split stat buffers (stride 512 floats)
__device__ inline void fin_ch4(const float* __restrict__ sum, const float* __restrict__ sq,
                               const float* __restrict__ g, const float* __restrict__ bb,
                               int o, float* __restrict__ al, float* __restrict__ cl) {
    float s = (sum[o] + sum[512 + o]) + (sum[1024 + o] + sum[1536 + o]);
    float q = (sq[o]  + sq[512 + o])  + (sq[1024 + o]  + sq[1536 + o]);
    float m = s * INV_M;
    float var = q * INV_M - m * m;
    float ai = g[o] * (1.0f / sqrtf(var + BN_EPS));
    al[o] = ai;
    cl[o] = bb[o] - m * ai;
}

// ---------------- front: blocks [0,4096) ball query; [4096,4104) weight pack + stat zero ----------------
__global__ void k_front(const float* __restrict__ xyz, const float* __restrict__ pts,
                        const int* __restrict__ fps, uint4* __restrict__ fbf,
                        const float* __restrict__ W1, const float* __restrict__ W2,
                        const float* __restrict__ W3, uint4* __restrict__ wf,
                        float* __restrict__ st) {
    __shared__ int lidx[4][NS];
    int tid = threadIdx.x;
    if (blockIdx.x >= 4096) {                      // ---- pack path ----
        int bb = blockIdx.x - 4096;
        if (bb == 7) {                             // zero 4x512 split stat buffers
            #pragma unroll
            for (int k = 0; k < 8; ++k) st[tid + k * 256] = 0.f;
            return;
        }
        int t = bb * 256 + tid;   // < 1792
        int l = t & 63, p = l & 15, qd = l >> 4;
        float v[8];
        if (t < 256) {
            int mt = t >> 6;
            #pragma unroll
            for (int j = 0; j < 8; ++j)
                v[j] = (qd == 0 && j < 6) ? W1[(mt * 16 + p) * 6 + j] : 0.f;   // A[m=o1][k=c]
        } else if (t < 768) {
            int fr = (t - 256) >> 6;
            int mt = fr >> 1, kf = fr & 1;
            #pragma unroll
            for (int j = 0; j < 8; ++j)
                v[j] = W2[(16 * mt + p) * 64 + kf * 32 + qd * 8 + j];          // A[m=o2][k=c]
        } else {
            int fr = (t - 768) >> 6;
            int nt = fr >> 1, kf = fr & 1;
            #pragma unroll
            for (int j = 0; j < 8; ++j)
                v[j] = W3[(nt * 16 + p) * 64 + kf * 32 + qd * 8 + j];          // B[k=c][n=o3]
        }
        uint4 o;
        o.x = pkbf(v[0], v[1]); o.y = pkbf(v[2], v[3]);
        o.z = pkbf(v[4], v[5]); o.w = pkbf(v[6], v[7]);
        wf[t] = o;
        return;
    }
    // ---- ball query path: prefetched scan, independent waves, no barrier ----
    int wave = (blockIdx.x * blockDim.x + tid) >> 6;
    int lane = tid & 63;
    int wslot = tid >> 6;
    int b = wave / SS_;
    const float* xb = xyz + (size_t)b * 3 * NN_;
    const float* pb = pts + (size_t)b * 3 * NN_;
    int ci = fps[wave];
    float cx = xb[ci], cy = xb[NN_ + ci], cz = xb[2 * NN_ + ci];

    float px = xb[lane], py = xb[NN_ + lane], pz = xb[2 * NN_ + lane];
    int found = 0;
    int first_i = -1;
    for (int base = 0; base < NN_; base += 64) {
        float xv = px, yv = py, zv = pz;
        int nb = (base + 64 < NN_) ? base + 64 : 0;
        px = xb[nb + lane]; py = xb[NN_ + nb + lane]; pz = xb[2 * NN_ + nb + lane];
        float dx = xv - cx, dy = yv - cy, dz = zv - cz;
        float d2 = __fadd_rn(__fadd_rn(__fmul_rn(dx, dx), __fmul_rn(dy, dy)), __fmul_rn(dz, dz));
        bool inr = d2 <= RAD2;
        unsigned long long mask = __ballot(inr);
        if (first_i < 0 && mask) first_i = base + __builtin_ctzll(mask);
        if (inr) {
            int pos = found + __popcll(mask & ((1ull << lane) - 1ull));
            if (pos < NS) lidx[wslot][pos] = base + lane;
        }
        found += __popcll(mask);
        if (found >= NS) break;
    }
    if (found > NS) found = NS;
    if (lane < NS) {
        int j = (lane < found) ? lidx[wslot][lane] : first_i;
        uint4 o;
        o.x = pkbf(xb[j] - cx,           xb[NN_ + j] - cy);
        o.y = pkbf(xb[2 * NN_ + j] - cz, pb[j]);
        o.z = pkbf(pb[NN_ + j],          pb[2 * NN_ + j]);
        o.w = 0u;
        fbf[(size_t)wave * NS + lane] = o;
    }
}

// ---------------- P1: f-sums + 6x6 Gram over bf16 feat (buffer 0 only) ----------------
__global__ void k_p1(const uint4* __restrict__ fbf, float* __restrict__ st) {
    __shared__ float sacc[27];
    int tid = threadIdx.x;
    if (tid < 27) sacc[tid] = 0.f;
    __syncthreads();
    int gt = blockIdx.x * 256 + tid;   // 262144 threads
    float vals[27];
    #pragma unroll
    for (int i = 0; i < 27; ++i) vals[i] = 0.f;
    #pragma unroll 1
    for (int it = 0; it < M_TOT / 262144; ++it) {
        uint4 w = fbf[it * 262144 + gt];
        float f[6] = { bflo(w.x), bfhi(w.x), bflo(w.y), bfhi(w.y), bflo(w.z), bfhi(w.z) };
        #pragma unroll
        for (int c = 0; c < 6; ++c) vals[c] += f[c];
        int q = 6;
        #pragma unroll
        for (int c = 0; c < 6; ++c)
            #pragma unroll
            for (int d = c; d < 6; ++d) { vals[q] = fmaf(f[c], f[d], vals[q]); ++q; }
    }
    int lane = tid & 63;
    #pragma unroll
    for (int i = 0; i < 27; ++i) {
        float v = vals[i];
        #pragma unroll
        for (int d = 32; d; d >>= 1) v += __shfl_xor(v, d);
        if (lane == 0) atomicAdd(&sacc[i], v);
    }
    __syncthreads();
    if (tid < 27) atomicAdd(&st[tid], sacc[tid]);
}

// ---------------- P2: layers 1-2 stats pass. SINGLE-WAVE blocks: 8192 x 64thr, 1 tile, 0 barriers ----------------
// LDS ~9.2 KB -> ~16 blocks/CU; stats via 4-way-split global atomics (blockIdx&3).
__global__ __launch_bounds__(64, 4) void k_p2(
        const uint4* __restrict__ fbf, const uint4* __restrict__ wpk,
        float* __restrict__ st,
        const float* __restrict__ W1, const float* __restrict__ g1, const float* __restrict__ b1) {
    __shared__ unsigned my[64 * YSTR];
    __shared__ float a1ls[C1], c1ls[C1];
    int lane = threadIdx.x;
    int p = lane & 15, qd = lane >> 4;
    int tile = blockIdx.x;                        // 8192 tiles
    float* stb = st + (blockIdx.x & 3) * 512;     // split stat buffer
    uint4 bv[4];
    #pragma unroll
    for (int nt = 0; nt < 4; ++nt) {              // issue first: overlaps fin1 prologue
        uint4 v = make_uint4(0u, 0u, 0u, 0u);
        if (qd == 0) v = fbf[tile * 64 + nt * 16 + p];
        bv[nt] = v;
    }
    fin1_ch(st, W1, g1, b1, lane, a1ls, c1ls);    // each lane: one channel
    asm volatile("" ::: "memory");                // LDS affine writes -> reads (same wave)
    const uint4* w1f = wpk;
    const uint4* w2f = wpk + 256;
    float s2[4][4], q2[4][4];
    #pragma unroll
    for (int i = 0; i < 4; ++i)
        #pragma unroll
        for (int r = 0; r < 4; ++r) { s2[i][r] = 0.f; q2[i][r] = 0.f; }

    #pragma unroll
    for (int mt = 0; mt < 4; ++mt) {
        bf16x8 A = asfrag(w1f[mt * 64 + lane]);
        float4 av = *(const float4*)(a1ls + mt * 16 + qd * 4);
        float4 cv = *(const float4*)(c1ls + mt * 16 + qd * 4);
        #pragma unroll
        for (int nt = 0; nt < 4; ++nt) {
            f32x4 acc = {0.f, 0.f, 0.f, 0.f};
            acc = __builtin_amdgcn_mfma_f32_16x16x32_bf16(A, asfrag(bv[nt]), acc, 0, 0, 0);
            float y0 = fmaxf(fmaf(av.x, acc[0], cv.x), 0.f);
            float y1 = fmaxf(fmaf(av.y, acc[1], cv.y), 0.f);
            float y2 = fmaxf(fmaf(av.z, acc[2], cv.z), 0.f);
            float y3 = fmaxf(fmaf(av.w, acc[3], cv.w), 0.f);
            int a = (nt * 16 + p) * YSTR + mt * 8 + qd * 2;
            *(uint2*)&my[a] = make_uint2(pkbf(y0, y1), pkbf(y2, y3));
        }
    }
    asm volatile("" ::: "memory");   // y1 writes -> B2 reads (wave-private LDS, in-order)
    bf16x8 B2[4][2];
    #pragma unroll
    for (int nt = 0; nt < 4; ++nt)
        #pragma unroll
        for (int kf = 0; kf < 2; ++kf)
            B2[nt][kf] = asfrag(*(const uint4*)&my[(nt * 16 + p) * YSTR + kf * 16 + qd * 4]);
    asm volatile("" ::: "memory");
    #pragma unroll
    for (int mt = 0; mt < 4; ++mt) {
        f32x4 acc[4];
        #pragma unroll
        for (int nt = 0; nt < 4; ++nt) acc[nt] = (f32x4){0.f, 0.f, 0.f, 0.f};
        #pragma unroll
        for (int kf = 0; kf < 2; ++kf) {
            bf16x8 W = asfrag(w2f[(mt * 2 + kf) * 64 + lane]);
            #pragma unroll
            for (int nt = 0; nt < 4; ++nt)
                acc[nt] = __builtin_amdgcn_mfma_f32_16x16x32_bf16(W, B2[nt][kf], acc[nt], 0, 0, 0);
        }
        #pragma unroll
        for (int r = 0; r < 4; ++r) {
            float u0 = acc[0][r], u1 = acc[1][r], u2 = acc[2][r], u3 = acc[3][r];
            s2[mt][r] += (u0 + u1) + (u2 + u3);
            q2[mt][r] = fmaf(u0, u0, fmaf(u1, u1, fmaf(u2, u2, fmaf(u3, u3, q2[mt][r]))));
        }
    }
    // stats reduce over p, then direct split-buffer atomics (4 lanes active per instr)
    #pragma unroll
    for (int mt = 0; mt < 4; ++mt)
        #pragma unroll
        for (int r = 0; r < 4; ++r) {
            float s = s2[mt][r], q = q2[mt][r];
            #pragma unroll
            for (int off = 1; off <= 8; off <<= 1) { s += __shfl_xor(s, off); q += __shfl_xor(q, off); }
            if (p == 0) {
                atomicAdd(&stb[64 + mt * 16 + qd * 4 + r], s);
                atomicAdd(&stb[128 + mt * 16 + qd * 4 + r], q);
            }
        }
}

// ---------------- P3: fused 3 layers. SINGLE-WAVE blocks: 8192 x 64thr, 1 tile, 0 barriers ----------------
// LDS ~9.7 KB -> ~16 blocks/CU; W3 frags from global (L1-hot) with 1-deep prefetch;
// stats via 4-way-split global atomics.
__global__ __launch_bounds__(64, 4) void k_p3_fused(
        const uint4* __restrict__ fbf, const uint4* __restrict__ wpk,
        float* __restrict__ st,
        const float* __restrict__ W1, const float* __restrict__ g1, const float* __restrict__ b1,
        const float* __restrict__ g2, const float* __restrict__ b2,
        const float* __restrict__ g3, float* __restrict__ gmm) {
    __shared__ unsigned my[64 * YSTR];
    __shared__ float a1ls[C1], c1ls[C1], a2ls[C2], c2ls[C2];
    int lane = threadIdx.x;
    int p = lane & 15, qd = lane >> 4;
    int tile = blockIdx.x;                        // 8192 tiles
    float* stb = st + (blockIdx.x & 3) * 512;
    uint4 bv[4];
    #pragma unroll
    for (int nt = 0; nt < 4; ++nt) {              // issue first: overlaps prologue
        uint4 v = make_uint4(0u, 0u, 0u, 0u);
        if (qd == 0) v = fbf[tile * 64 + nt * 16 + p];
        bv[nt] = v;
    }
    unsigned posm = 0;
    #pragma unroll
    for (int i = 0; i < 8; ++i) posm |= (g3[i * 16 + p] >= 0.f) ? (1u << i) : 0u;
    fin1_ch(st, W1, g1, b1, lane, a1ls, c1ls);
    fin_ch4(st + 64, st + 128, g2, b2, lane, a2ls, c2ls);
    asm volatile("" ::: "memory");                // affine LDS writes -> reads (same wave)
    const uint4* w1f = wpk;
    const uint4* w2f = wpk + 256;
    const uint4* w3f = wpk + 768;

    // ---- L1 ----
    #pragma unroll
    for (int mt = 0; mt < 4; ++mt) {
        bf16x8 Aw = asfrag(w1f[mt * 64 + lane]);
        float4 av = *(const float4*)(a1ls + mt * 16 + qd * 4);
        float4 cv = *(const float4*)(c1ls + mt * 16 + qd * 4);
        #pragma unroll
        for (int nt = 0; nt < 4; ++nt) {
            f32x4 acc = {0.f, 0.f, 0.f, 0.f};
            acc = __builtin_amdgcn_mfma_f32_16x16x32_bf16(Aw, asfrag(bv[nt]), acc, 0, 0, 0);
            float y0 = fmaxf(fmaf(av.x, acc[0], cv.x), 0.f);
            float y1 = fmaxf(fmaf(av.y, acc[1], cv.y), 0.f);
            float y2 = fmaxf(fmaf(av.z, acc[2], cv.z), 0.f);
            float y3 = fmaxf(fmaf(av.w, acc[3], cv.w), 0.f);
            int a = (nt * 16 + p) * YSTR + mt * 8 + qd * 2;
            *(uint2*)&my[a] = make_uint2(pkbf(y0, y1), pkbf(y2, y3));
        }
    }
    asm volatile("" ::: "memory");
    bf16x8 B2[4][2];
    #pragma unroll
    for (int nt = 0; nt < 4; ++nt)
        #pragma unroll
        for (int kf = 0; kf < 2; ++kf)
            B2[nt][kf] = asfrag(*(const uint4*)&my[(nt * 16 + p) * YSTR + kf * 16 + qd * 4]);
    asm volatile("" ::: "memory");
    // ---- L2 ----
    #pragma unroll
    for (int mt = 0; mt < 4; ++mt) {
        f32x4 acc[4];
        #pragma unroll
        for (int nt = 0; nt < 4; ++nt) acc[nt] = (f32x4){0.f, 0.f, 0.f, 0.f};
        #pragma unroll
        for (int kf = 0; kf < 2; ++kf) {
            bf16x8 W = asfrag(w2f[(mt * 2 + kf) * 64 + lane]);
            #pragma unroll
            for (int nt = 0; nt < 4; ++nt)
                acc[nt] = __builtin_amdgcn_mfma_f32_16x16x32_bf16(W, B2[nt][kf], acc[nt], 0, 0, 0);
        }
        float4 av = *(const float4*)(a2ls + mt * 16 + qd * 4);
        float4 cv = *(const float4*)(c2ls + mt * 16 + qd * 4);
        #pragma unroll
        for (int nt = 0; nt < 4; ++nt) {
            float y0 = fmaxf(fmaf(av.x, acc[nt][0], cv.x), 0.f);
            float y1 = fmaxf(fmaf(av.y, acc[nt][1], cv.y), 0.f);
            float y2 = fmaxf(fmaf(av.z, acc[nt][2], cv.z), 0.f);
            float y3 = fmaxf(fmaf(av.w, acc[nt][3], cv.w), 0.f);
            int a = (nt * 16 + p) * YSTR + mt * 8 + qd * 2;
            *(uint2*)&my[a] = make_uint2(pkbf(y0, y1), pkbf(y2, y3));
        }
    }
    asm volatile("" ::: "memory");
    bf16x8 A3[4][2];
    #pragma unroll
    for (int mt = 0; mt < 4; ++mt) {
        A3[mt][0] = asfrag(*(const uint4*)&my[(mt * 16 + p) * YSTR + qd * 4]);
        A3[mt][1] = asfrag(*(const uint4*)&my[(mt * 16 + p) * YSTR + 16 + qd * 4]);
    }
    asm volatile("" ::: "memory");
    // ---- L3: runtime nt loop, W-frag 1-deep double buffer ----
    uint4 wva = w3f[lane];
    uint4 wvb = w3f[64 + lane];
    #pragma unroll 1
    for (int nt = 0; nt < 8; ++nt) {
        int nn = (nt < 7) ? nt + 1 : 7;
        uint4 nwa = w3f[(nn * 2 + 0) * 64 + lane];   // prefetch next W pair
        uint4 nwb = w3f[(nn * 2 + 1) * 64 + lane];
        bf16x8 Wa = asfrag(wva), Wb = asfrag(wvb);
        f32x4 acc[4];
        #pragma unroll
        for (int mt = 0; mt < 4; ++mt) {
            acc[mt] = __builtin_amdgcn_mfma_f32_16x16x32_bf16(A3[mt][0], Wa,
                        (f32x4){0.f, 0.f, 0.f, 0.f}, 0, 0, 0);
            acc[mt] = __builtin_amdgcn_mfma_f32_16x16x32_bf16(A3[mt][1], Wb, acc[mt], 0, 0, 0);
        }
        bool pn = (posm >> nt) & 1;
        float s = 0.f, q = 0.f, va = 0.f, vb = 0.f;
        #pragma unroll
        for (int mt = 0; mt < 4; ++mt) {
            float v0 = acc[mt][0], v1 = acc[mt][1], v2 = acc[mt][2], v3 = acc[mt][3];
            s += (v0 + v1) + (v2 + v3);
            q = fmaf(v0, v0, fmaf(v1, v1, fmaf(v2, v2, fmaf(v3, v3, q))));
            float mx = fmaxf(fmaxf(v0, v1), fmaxf(v2, v3));
            float mn = fminf(fminf(v0, v1), fminf(v2, v3));
            float vv = pn ? mx : -mn;
            if (mt == 0) va = vv;
            else if (mt == 1) va = fmaxf(va, vv);
            else if (mt == 2) vb = vv;
            else vb = fmaxf(vb, vv);
        }
        s += __shfl_xor(s, 16); s += __shfl_xor(s, 32);
        q += __shfl_xor(q, 16); q += __shfl_xor(q, 32);
        va = fmaxf(va, __shfl_xor(va, 16)); va = fmaxf(va, __shfl_xor(va, 32));
        vb = fmaxf(vb, __shfl_xor(vb, 16)); vb = fmaxf(vb, __shfl_xor(vb, 32));
        if (lane < 16) {
            gmm[(size_t)(tile * 2 + 0) * C3 + nt * 16 + lane] = va;
            gmm[(size_t)(tile * 2 + 1) * C3 + nt * 16 + lane] = vb;
            atomicAdd(&stb[192 + nt * 16 + lane], s);
            atomicAdd(&stb[320 + nt * 16 + lane], q);
        }
        wva = nwa; wvb = nwb;
    }
}

// ---------------- epilogue: fin3 inlined (4-buffer sums); coalesced gmm read; out + xyz ----------------
__global__ void k_outx(const float* __restrict__ gmm, const float* __restrict__ st,
                       const float* __restrict__ g3, const float* __restrict__ b3,
                       const float* __restrict__ xyz, const int* __restrict__ fps,
                       float* __restrict__ out) {
    __shared__ float T[C3][17];
    __shared__ float a3ls[C3], c3ls[C3];
    int blk = blockIdx.x, tid = threadIdx.x;
    if (blk < 1024) {
        if (tid < C3) fin_ch4(st + 192, st + 320, g3, b3, tid, a3ls, c3ls);
        __syncthreads();
        int b = blk >> 7, s0 = (blk & 127) << 4;
        #pragma unroll
        for (int i = 0; i < 8; ++i) {
            int idx = i * 256 + tid;
            int sl = idx >> 7, o = idx & 127;
            float m = gmm[((size_t)(b * SS_ + s0 + sl)) * C3 + o];
            float a = a3ls[o];
            float v = (a >= 0.f) ? m : -m;
            T[o][sl] = fmaxf(fmaf(a, v, c3ls[o]), 0.f);
        }
        __syncthreads();
        int o = tid & 127, sh = tid >> 7;
        float* dst = out + (size_t)BB_ * 3 * SS_ + ((size_t)b * C3 + o) * SS_ + s0 + sh * 8;
        float4 w0, w1;
        w0.x = T[o][sh * 8 + 0]; w0.y = T[o][sh * 8 + 1];
        w0.z = T[o][sh * 8 + 2]; w0.w = T[o][sh * 8 + 3];
        w1.x = T[o][sh * 8 + 4]; w1.y = T[o][sh * 8 + 5];
        w1.z = T[o][sh * 8 + 6]; w1.w = T[o][sh * 8 + 7];
        *(float4*)dst = w0; *(float4*)(dst + 4) = w1;
    } else {
        int t = (blk - 1024) * 256 + tid;   // < 49152
        int b = t / (3 * SS_);
        int r = (t / SS_) % 3;
        int s = t % SS_;
        int ci = fps[b * SS_ + s];
        out[t] = xyz[((size_t)b * 3 + r) * NN_ + ci];
    }
}

extern "C" void kernel_launch(void* const* d_in, const int* in_sizes, int n_in,
                              void* d_out, int out_size, void* d_ws, size_t ws_size,
                              hipStream_t stream) {
    (void)in_sizes; (void)n_in; (void)out_size; (void)ws_size;
    const float* xyz = (const float*)d_in[0];
    const float* pts = (const float*)d_in[1];
    const int*   fps = (const int*)d_in[2];
    const float* W1 = (const float*)d_in[3];
    const float* g1 = (const float*)d_in[4];
    const float* b1 = (const float*)d_in[5];
    const float* W2 = (const float*)d_in[6];
    const float* g2 = (const float*)d_in[7];
    const float* b2 = (const float*)d_in[8];
    const float* W3 = (const float*)d_in[9];
    const float* g3 = (const float*)d_in[10];
    const float* b3 = (const float*)d_in[11];
    float* out = (float*)d_out;
    float* ws = (float*)d_ws;

    uint4* fbf = (uint4*)(ws + FBF_OFF);
    uint4* wpk = (uint4*)(ws + WPK_OFF);
    float* st  = ws + ST_OFF;
    float* gmm = ws + GMM_OFF;

    k_front<<<4096 + 8, 256, 0, stream>>>(xyz, pts, fps, fbf, W1, W2, W3, wpk, st);
    k_p1<<<1024, 256, 0, stream>>>(fbf, st);
    k_p2<<<8192, 64, 0, stream>>>(fbf, wpk, st, W1, g1, b1);
    k_p3_fused<<<8192, 64, 0, stream>>>(fbf, wpk, st, W1, g1, b1, g2, b2, g3, gmm);
    k_outx<<<1024 + 192, 256, 0, stream>>>(gmm, st, g3, b3, xyz, fps, out);
}

// Round 7
// 265.941 us; speedup vs baseline: 1.6680x; 1.6680x over previous
//
#include <hip/hip_runtime.h>
#include <hip/hip_bf16.h>

#define BB_ 8
#define NN_ 8192
#define SS_ 2048
#define NS 32
#define C1 64
#define C2 64
#define C3 128
#define RAD2 0.04f
#define BN_EPS 1e-5f
#define M_TOT (BB_*SS_*NS)   // 524288
#define INV_M (1.0f/524288.0f)
#define YSTR 34              // LDS row stride (dwords): conflict-free frag reads

typedef __attribute__((ext_vector_type(8))) short bf16x8;
typedef __attribute__((ext_vector_type(4))) float f32x4;

// ws float offsets
#define FBF_OFF 0          // feat bf16 [M_TOT][8] = 2,097,152 floats (8 MB)
#define WPK_OFF 2097152    // packed weight frags: 1792 uint4
#define ST_OFF  2104320    // 512: gram[27] | sum2@64 sq2@128 | sum3@192 sq3@320
#define GMM_OFF 2104832    // float per (group, o3): 16384*128 = 2,097,152 floats (8 MB)

__device__ inline unsigned pkbf(float a, float b) {
    __hip_bfloat162 h = __float22bfloat162_rn(make_float2(a, b));
    unsigned r; __builtin_memcpy(&r, &h, 4); return r;
}
__device__ inline bf16x8 asfrag(uint4 v) { bf16x8 r; __builtin_memcpy(&r, &v, 16); return r; }
__device__ inline float bflo(unsigned u) { unsigned x = u << 16; float f; __builtin_memcpy(&f, &x, 4); return f; }
__device__ inline float bfhi(unsigned u) { unsigned x = u & 0xffff0000u; float f; __builtin_memcpy(&f, &x, 4); return f; }

__device__ inline void fin1_ch(const float* __restrict__ st, const float* __restrict__ W1,
                               const float* __restrict__ g, const float* __restrict__ bb,
                               int o, float* __restrict__ al, float* __restrict__ cl) {
    float w[6];
    #pragma unroll
    for (int i = 0; i < 6; ++i) w[i] = W1[o * 6 + i];
    float ms = 0.f;
    #pragma unroll
    for (int i = 0; i < 6; ++i) ms = fmaf(w[i], st[i], ms);
    float m = ms * INV_M;
    float e2 = 0.f;
    #pragma unroll
    for (int ci = 0; ci < 6; ++ci)
        #pragma unroll
        for (int d = 0; d < 6; ++d) {
            int lo = ci < d ? ci : d, hi = ci < d ? d : ci;
            int idx = 6 + lo * 6 - lo * (lo + 1) / 2 + hi;
            e2 = fmaf(w[ci] * w[d], st[idx], e2);
        }
    float var = e2 * INV_M - m * m;
    float ai = g[o] * (1.0f / sqrtf(var + BN_EPS));
    al[o] = ai;
    cl[o] = bb[o] - m * ai;
}

__device__ inline void fin_ch(const float* __restrict__ sum, const float* __restrict__ sq,
                              const float* __restrict__ g, const float* __restrict__ bb,
                              int o, float* __restrict__ al, float* __restrict__ cl) {
    float m = sum[o] * INV_M;
    float var = sq[o] * INV_M - m * m;
    float ai = g[o] * (1.0f / sqrtf(var + BN_EPS));
    al[o] = ai;
    cl[o] = bb[o] - m * ai;
}

// ---------------- front: blocks [0,4096) ball query + GRAM FOLD; [4096,4103) weight pack ----------------
// Gram (p1) folded in: each lane's neighbor features are in registers at fbf-write time.
// st must be zeroed BEFORE this kernel (hipMemsetAsync in launcher).
__global__ void k_front(const float* __restrict__ xyz, const float* __restrict__ pts,
                        const int* __restrict__ fps, uint4* __restrict__ fbf,
                        const float* __restrict__ W1, const float* __restrict__ W2,
                        const float* __restrict__ W3, uint4* __restrict__ wf,
                        float* __restrict__ st) {
    __shared__ int lidx[4][NS];
    __shared__ float sacc[27];
    int tid = threadIdx.x;
    if (blockIdx.x >= 4096) {                      // ---- pack path (7 blocks, t < 1792) ----
        int bb = blockIdx.x - 4096;
        int t = bb * 256 + tid;
        int l = t & 63, p = l & 15, qd = l >> 4;
        float v[8];
        if (t < 256) {
            int mt = t >> 6;
            #pragma unroll
            for (int j = 0; j < 8; ++j)
                v[j] = (qd == 0 && j < 6) ? W1[(mt * 16 + p) * 6 + j] : 0.f;   // A[m=o1][k=c]
        } else if (t < 768) {
            int fr = (t - 256) >> 6;
            int mt = fr >> 1, kf = fr & 1;
            #pragma unroll
            for (int j = 0; j < 8; ++j)
                v[j] = W2[(16 * mt + p) * 64 + kf * 32 + qd * 8 + j];          // A[m=o2][k=c]
        } else {
            int fr = (t - 768) >> 6;
            int nt = fr >> 1, kf = fr & 1;
            #pragma unroll
            for (int j = 0; j < 8; ++j)
                v[j] = W3[(nt * 16 + p) * 64 + kf * 32 + qd * 8 + j];          // B[k=c][n=o3]
        }
        uint4 o;
        o.x = pkbf(v[0], v[1]); o.y = pkbf(v[2], v[3]);
        o.z = pkbf(v[4], v[5]); o.w = pkbf(v[6], v[7]);
        wf[t] = o;
        return;
    }
    // ---- ball query path ----
    if (tid < 27) sacc[tid] = 0.f;
    __syncthreads();
    int wave = (blockIdx.x * blockDim.x + tid) >> 6;
    int lane = tid & 63;
    int wslot = tid >> 6;
    int b = wave / SS_;
    const float* xb = xyz + (size_t)b * 3 * NN_;
    const float* pb = pts + (size_t)b * 3 * NN_;
    int ci = fps[wave];
    float cx = xb[ci], cy = xb[NN_ + ci], cz = xb[2 * NN_ + ci];

    float px = xb[lane], py = xb[NN_ + lane], pz = xb[2 * NN_ + lane];
    int found = 0;
    int first_i = -1;
    for (int base = 0; base < NN_; base += 64) {
        float xv = px, yv = py, zv = pz;
        int nb = (base + 64 < NN_) ? base + 64 : 0;
        px = xb[nb + lane]; py = xb[NN_ + nb + lane]; pz = xb[2 * NN_ + nb + lane];
        float dx = xv - cx, dy = yv - cy, dz = zv - cz;
        float d2 = __fadd_rn(__fadd_rn(__fmul_rn(dx, dx), __fmul_rn(dy, dy)), __fmul_rn(dz, dz));
        bool inr = d2 <= RAD2;
        unsigned long long mask = __ballot(inr);
        if (first_i < 0 && mask) first_i = base + __builtin_ctzll(mask);
        if (inr) {
            int pos = found + __popcll(mask & ((1ull << lane) - 1ull));
            if (pos < NS) lidx[wslot][pos] = base + lane;
        }
        found += __popcll(mask);
        if (found >= NS) break;
    }
    if (found > NS) found = NS;
    float f0 = 0.f, f1 = 0.f, f2 = 0.f, f3 = 0.f, f4 = 0.f, f5 = 0.f;
    if (lane < NS) {
        int j = (lane < found) ? lidx[wslot][lane] : first_i;
        f0 = xb[j] - cx;           f1 = xb[NN_ + j] - cy;
        f2 = xb[2 * NN_ + j] - cz; f3 = pb[j];
        f4 = pb[NN_ + j];          f5 = pb[2 * NN_ + j];
        uint4 o;
        o.x = pkbf(f0, f1);
        o.y = pkbf(f2, f3);
        o.z = pkbf(f4, f5);
        o.w = 0u;
        fbf[(size_t)wave * NS + lane] = o;
    }
    // gram: each lane contributes one point's sums and products
    float f[6] = { f0, f1, f2, f3, f4, f5 };
    float vals[27];
    #pragma unroll
    for (int c = 0; c < 6; ++c) vals[c] = f[c];
    {
        int q = 6;
        #pragma unroll
        for (int c = 0; c < 6; ++c)
            #pragma unroll
            for (int d = c; d < 6; ++d) { vals[q] = f[c] * f[d]; ++q; }
    }
    #pragma unroll
    for (int i = 0; i < 27; ++i) {
        float v = vals[i];
        #pragma unroll
        for (int d = 32; d; d >>= 1) v += __shfl_xor(v, d);
        if (lane == 0) atomicAdd(&sacc[i], v);
    }
    __syncthreads();
    if (tid < 27) atomicAdd(&st[tid], sacc[tid]);
}

// ---------------- P2: layers 1-2 stats pass. Barrier-free inner pipeline (R5-verified) ----------------
__global__ __launch_bounds__(256, 4) void k_p2(
        const uint4* __restrict__ fbf, const uint4* __restrict__ wpk,
        float* __restrict__ st,
        const float* __restrict__ W1, const float* __restrict__ g1, const float* __restrict__ b1) {
    __shared__ unsigned yls[4][64 * YSTR];
    __shared__ float bs[C2], bq[C2];
    __shared__ float a1ls[C1], c1ls[C1];
    int tid = threadIdx.x, wslot = tid >> 6, lane = tid & 63;
    int p = lane & 15, qd = lane >> 4;
    int tile0 = blockIdx.x * 8 + wslot;           // wave tiles: tile0, tile0+4
    uint4 bv[4];
    #pragma unroll
    for (int nt = 0; nt < 4; ++nt) {              // issue early: overlaps prologue
        uint4 v = make_uint4(0u, 0u, 0u, 0u);
        if (qd == 0) v = fbf[tile0 * 64 + nt * 16 + p];
        bv[nt] = v;
    }
    bf16x8 w1r[4];
    #pragma unroll
    for (int mt = 0; mt < 4; ++mt) w1r[mt] = asfrag(wpk[mt * 64 + lane]);   // hoisted L1 weights
    if (tid < C2) { bs[tid] = 0.f; bq[tid] = 0.f; fin1_ch(st, W1, g1, b1, tid, a1ls, c1ls); }
    __syncthreads();
    const uint4* w2f = wpk + 256;
    unsigned* my = yls[wslot];
    float s2[4][4], q2[4][4];
    #pragma unroll
    for (int i = 0; i < 4; ++i)
        #pragma unroll
        for (int r = 0; r < 4; ++r) { s2[i][r] = 0.f; q2[i][r] = 0.f; }

    #pragma unroll
    for (int t = 0; t < 2; ++t) {
        uint4 nbv[4];
        if (t == 0) {
            #pragma unroll
            for (int nt = 0; nt < 4; ++nt) {      // prefetch second tile
                uint4 v = make_uint4(0u, 0u, 0u, 0u);
                if (qd == 0) v = fbf[(tile0 + 4) * 64 + nt * 16 + p];
                nbv[nt] = v;
            }
        }
        bf16x8 B1[4];
        #pragma unroll
        for (int nt = 0; nt < 4; ++nt) B1[nt] = asfrag(bv[nt]);
        #pragma unroll
        for (int mt = 0; mt < 4; ++mt) {
            bf16x8 A = w1r[mt];
            float4 av = *(const float4*)(a1ls + mt * 16 + qd * 4);
            float4 cv = *(const float4*)(c1ls + mt * 16 + qd * 4);
            #pragma unroll
            for (int nt = 0; nt < 4; ++nt) {
                f32x4 acc = {0.f, 0.f, 0.f, 0.f};
                acc = __builtin_amdgcn_mfma_f32_16x16x32_bf16(A, B1[nt], acc, 0, 0, 0);
                float y0 = fmaxf(fmaf(av.x, acc[0], cv.x), 0.f);
                float y1 = fmaxf(fmaf(av.y, acc[1], cv.y), 0.f);
                float y2 = fmaxf(fmaf(av.z, acc[2], cv.z), 0.f);
                float y3 = fmaxf(fmaf(av.w, acc[3], cv.w), 0.f);
                int a = (nt * 16 + p) * YSTR + mt * 8 + qd * 2;
                *(uint2*)&my[a] = make_uint2(pkbf(y0, y1), pkbf(y2, y3));
            }
        }
        asm volatile("" ::: "memory");   // y1 writes -> B2 reads (wave-private LDS)
        bf16x8 B2[4][2];
        #pragma unroll
        for (int nt = 0; nt < 4; ++nt)
            #pragma unroll
            for (int kf = 0; kf < 2; ++kf)
                B2[nt][kf] = asfrag(*(const uint4*)&my[(nt * 16 + p) * YSTR + kf * 16 + qd * 4]);
        asm volatile("" ::: "memory");
        #pragma unroll
        for (int mt = 0; mt < 4; ++mt) {
            f32x4 acc[4];
            #pragma unroll
            for (int nt = 0; nt < 4; ++nt) acc[nt] = (f32x4){0.f, 0.f, 0.f, 0.f};
            #pragma unroll
            for (int kf = 0; kf < 2; ++kf) {
                bf16x8 W = asfrag(w2f[(mt * 2 + kf) * 64 + lane]);
                #pragma unroll
                for (int nt = 0; nt < 4; ++nt)
                    acc[nt] = __builtin_amdgcn_mfma_f32_16x16x32_bf16(W, B2[nt][kf], acc[nt], 0, 0, 0);
            }
            #pragma unroll
            for (int r = 0; r < 4; ++r) {
                float u0 = acc[0][r], u1 = acc[1][r], u2 = acc[2][r], u3 = acc[3][r];
                s2[mt][r] += (u0 + u1) + (u2 + u3);
                q2[mt][r] = fmaf(u0, u0, fmaf(u1, u1, fmaf(u2, u2, fmaf(u3, u3, q2[mt][r]))));
            }
        }
        if (t == 0) {
            #pragma unroll
            for (int nt = 0; nt < 4; ++nt) bv[nt] = nbv[nt];
        }
        asm volatile("" ::: "memory");   // LDS reuse before next tile's stage A
    }
    // stats reduce over p + block + global
    #pragma unroll
    for (int mt = 0; mt < 4; ++mt)
        #pragma unroll
        for (int r = 0; r < 4; ++r) {
            float s = s2[mt][r], q = q2[mt][r];
            #pragma unroll
            for (int off = 1; off <= 8; off <<= 1) { s += __shfl_xor(s, off); q += __shfl_xor(q, off); }
            if (p == 0) {
                atomicAdd(&bs[mt * 16 + qd * 4 + r], s);
                atomicAdd(&bq[mt * 16 + qd * 4 + r], q);
            }
        }
    __syncthreads();
    if (tid < C2) { atomicAdd(&st[64 + tid], bs[tid]); atomicAdd(&st[128 + tid], bq[tid]); }
}

// ---------------- P3: fused 3 layers from fbf (R5-verified 57us) + both-tile load hoist ----------------
__global__ __launch_bounds__(256, 4) void k_p3_fused(
        const uint4* __restrict__ fbf, const uint4* __restrict__ wpk,
        float* __restrict__ st,
        const float* __restrict__ W1, const float* __restrict__ g1, const float* __restrict__ b1,
        const float* __restrict__ g2, const float* __restrict__ b2,
        const float* __restrict__ g3, float* __restrict__ gmm) {
    __shared__ unsigned yls[4][64 * YSTR];
    __shared__ float bs[C3], bq[C3];
    __shared__ float a1ls[C1], c1ls[C1], a2ls[C2], c2ls[C2];
    int tid = threadIdx.x, wslot = tid >> 6, lane = tid & 63;
    int p = lane & 15, qd = lane >> 4;
    int tile0 = blockIdx.x * 4 + wslot;
    uint4 bv0[4], bv1[4];
    #pragma unroll
    for (int nt = 0; nt < 4; ++nt) {              // hoist BOTH tiles' loads: overlap prologue+barrier
        uint4 v0 = make_uint4(0u, 0u, 0u, 0u);
        uint4 v1 = make_uint4(0u, 0u, 0u, 0u);
        if (qd == 0) {
            v0 = fbf[tile0 * 64 + nt * 16 + p];
            v1 = fbf[(tile0 + 4096) * 64 + nt * 16 + p];
        }
        bv0[nt] = v0; bv1[nt] = v1;
    }
    unsigned posm = 0;
    #pragma unroll
    for (int i = 0; i < 8; ++i) posm |= (g3[i * 16 + p] >= 0.f) ? (1u << i) : 0u;
    if (tid < 128) bs[tid] = 0.f; else bq[tid - 128] = 0.f;
    if (tid < 64) fin1_ch(st, W1, g1, b1, tid, a1ls, c1ls);
    else if (tid < 128) fin_ch(st + 64, st + 128, g2, b2, tid - 64, a2ls, c2ls);
    __syncthreads();
    const uint4* w1f = wpk;
    const uint4* w2f = wpk + 256;
    const uint4* w3f = wpk + 768;
    unsigned* my = yls[wslot];

    #pragma unroll
    for (int it = 0; it < 2; ++it) {
        int tile = tile0 + it * 4096;
        // ---- L1 ----
        #pragma unroll
        for (int mt = 0; mt < 4; ++mt) {
            bf16x8 Aw = asfrag(w1f[mt * 64 + lane]);
            float4 av = *(const float4*)(a1ls + mt * 16 + qd * 4);
            float4 cv = *(const float4*)(c1ls + mt * 16 + qd * 4);
            #pragma unroll
            for (int nt = 0; nt < 4; ++nt) {
                uint4 bcur = (it == 0) ? bv0[nt] : bv1[nt];   // it is compile-time (unrolled)
                f32x4 acc = {0.f, 0.f, 0.f, 0.f};
                acc = __builtin_amdgcn_mfma_f32_16x16x32_bf16(Aw, asfrag(bcur), acc, 0, 0, 0);
                float y0 = fmaxf(fmaf(av.x, acc[0], cv.x), 0.f);
                float y1 = fmaxf(fmaf(av.y, acc[1], cv.y), 0.f);
                float y2 = fmaxf(fmaf(av.z, acc[2], cv.z), 0.f);
                float y3 = fmaxf(fmaf(av.w, acc[3], cv.w), 0.f);
                int a = (nt * 16 + p) * YSTR + mt * 8 + qd * 2;
                *(uint2*)&my[a] = make_uint2(pkbf(y0, y1), pkbf(y2, y3));
            }
        }
        asm volatile("" ::: "memory");   // y1 writes -> B2 reads (wave-private LDS)
        bf16x8 B2[4][2];
        #pragma unroll
        for (int nt = 0; nt < 4; ++nt)
            #pragma unroll
            for (int kf = 0; kf < 2; ++kf)
                B2[nt][kf] = asfrag(*(const uint4*)&my[(nt * 16 + p) * YSTR + kf * 16 + qd * 4]);
        asm volatile("" ::: "memory");
        // ---- L2 ----
        #pragma unroll
        for (int mt = 0; mt < 4; ++mt) {
            f32x4 acc[4];
            #pragma unroll
            for (int nt = 0; nt < 4; ++nt) acc[nt] = (f32x4){0.f, 0.f, 0.f, 0.f};
            #pragma unroll
            for (int kf = 0; kf < 2; ++kf) {
                bf16x8 W = asfrag(w2f[(mt * 2 + kf) * 64 + lane]);
                #pragma unroll
                for (int nt = 0; nt < 4; ++nt)
                    acc[nt] = __builtin_amdgcn_mfma_f32_16x16x32_bf16(W, B2[nt][kf], acc[nt], 0, 0, 0);
            }
            float4 av = *(const float4*)(a2ls + mt * 16 + qd * 4);
            float4 cv = *(const float4*)(c2ls + mt * 16 + qd * 4);
            #pragma unroll
            for (int nt = 0; nt < 4; ++nt) {
                float y0 = fmaxf(fmaf(av.x, acc[nt][0], cv.x), 0.f);
                float y1 = fmaxf(fmaf(av.y, acc[nt][1], cv.y), 0.f);
                float y2 = fmaxf(fmaf(av.z, acc[nt][2], cv.z), 0.f);
                float y3 = fmaxf(fmaf(av.w, acc[nt][3], cv.w), 0.f);
                int a = (nt * 16 + p) * YSTR + mt * 8 + qd * 2;
                *(uint2*)&my[a] = make_uint2(pkbf(y0, y1), pkbf(y2, y3));
            }
        }
        asm volatile("" ::: "memory");   // x2 writes -> A3 reads (wave-private LDS)
        bf16x8 A3[4][2];
        #pragma unroll
        for (int mt = 0; mt < 4; ++mt) {
            A3[mt][0] = asfrag(*(const uint4*)&my[(mt * 16 + p) * YSTR + qd * 4]);
            A3[mt][1] = asfrag(*(const uint4*)&my[(mt * 16 + p) * YSTR + 16 + qd * 4]);
        }
        asm volatile("" ::: "memory");
        // ---- L3: runtime nt loop, W-frag 1-deep double buffer ----
        uint4 wva = w3f[lane];
        uint4 wvb = w3f[64 + lane];
        #pragma unroll 1
        for (int nt = 0; nt < 8; ++nt) {
            int nn = (nt < 7) ? nt + 1 : 7;
            uint4 nwa = w3f[(nn * 2 + 0) * 64 + lane];   // prefetch next W pair
            uint4 nwb = w3f[(nn * 2 + 1) * 64 + lane];
            bf16x8 Wa = asfrag(wva), Wb = asfrag(wvb);
            f32x4 acc[4];
            #pragma unroll
            for (int mt = 0; mt < 4; ++mt) {
                acc[mt] = __builtin_amdgcn_mfma_f32_16x16x32_bf16(A3[mt][0], Wa,
                            (f32x4){0.f, 0.f, 0.f, 0.f}, 0, 0, 0);
                acc[mt] = __builtin_amdgcn_mfma_f32_16x16x32_bf16(A3[mt][1], Wb, acc[mt], 0, 0, 0);
            }
            bool pn = (posm >> nt) & 1;
            float s = 0.f, q = 0.f, va = 0.f, vb = 0.f;
            #pragma unroll
            for (int mt = 0; mt < 4; ++mt) {
                float v0 = acc[mt][0], v1 = acc[mt][1], v2 = acc[mt][2], v3 = acc[mt][3];
                s += (v0 + v1) + (v2 + v3);
                q = fmaf(v0, v0, fmaf(v1, v1, fmaf(v2, v2, fmaf(v3, v3, q))));
                float mx = fmaxf(fmaxf(v0, v1), fmaxf(v2, v3));
                float mn = fminf(fminf(v0, v1), fminf(v2, v3));
                float vv = pn ? mx : -mn;
                if (mt == 0) va = vv;
                else if (mt == 1) va = fmaxf(va, vv);
                else if (mt == 2) vb = vv;
                else vb = fmaxf(vb, vv);
            }
            s += __shfl_xor(s, 16); s += __shfl_xor(s, 32);
            q += __shfl_xor(q, 16); q += __shfl_xor(q, 32);
            va = fmaxf(va, __shfl_xor(va, 16)); va = fmaxf(va, __shfl_xor(va, 32));
            vb = fmaxf(vb, __shfl_xor(vb, 16)); vb = fmaxf(vb, __shfl_xor(vb, 32));
            if (lane < 16) {
                gmm[(size_t)(tile * 2 + 0) * C3 + nt * 16 + lane] = va;
                gmm[(size_t)(tile * 2 + 1) * C3 + nt * 16 + lane] = vb;
                atomicAdd(&bs[nt * 16 + lane], s);
                atomicAdd(&bq[nt * 16 + lane], q);
            }
            wva = nwa; wvb = nwb;
        }
    }
    __syncthreads();
    if (tid < C3) { atomicAdd(&st[192 + tid], bs[tid]); atomicAdd(&st[320 + tid], bq[tid]); }
}

// ---------------- epilogue: fin3 inlined; coalesced gmm read; out + xyz ----------------
__global__ void k_outx(const float* __restrict__ gmm, const float* __restrict__ st,
                       const float* __restrict__ g3, const float* __restrict__ b3,
                       const float* __restrict__ xyz, const int* __restrict__ fps,
                       float* __restrict__ out) {
    __shared__ float T[C3][17];
    __shared__ float a3ls[C3], c3ls[C3];
    int blk = blockIdx.x, tid = threadIdx.x;
    if (blk < 1024) {
        if (tid < C3) fin_ch(st + 192, st + 320, g3, b3, tid, a3ls, c3ls);
        __syncthreads();
        int b = blk >> 7, s0 = (blk & 127) << 4;
        #pragma unroll
        for (int i = 0; i < 8; ++i) {
            int idx = i * 256 + tid;
            int sl = idx >> 7, o = idx & 127;
            float m = gmm[((size_t)(b * SS_ + s0 + sl)) * C3 + o];
            float a = a3ls[o];
            float v = (a >= 0.f) ? m : -m;
            T[o][sl] = fmaxf(fmaf(a, v, c3ls[o]), 0.f);
        }
        __syncthreads();
        int o = tid & 127, sh = tid >> 7;
        float* dst = out + (size_t)BB_ * 3 * SS_ + ((size_t)b * C3 + o) * SS_ + s0 + sh * 8;
        float4 w0, w1;
        w0.x = T[o][sh * 8 + 0]; w0.y = T[o][sh * 8 + 1];
        w0.z = T[o][sh * 8 + 2]; w0.w = T[o][sh * 8 + 3];
        w1.x = T[o][sh * 8 + 4]; w1.y = T[o][sh * 8 + 5];
        w1.z = T[o][sh * 8 + 6]; w1.w = T[o][sh * 8 + 7];
        *(float4*)dst = w0; *(float4*)(dst + 4) = w1;
    } else {
        int t = (blk - 1024) * 256 + tid;   // < 49152
        int b = t / (3 * SS_);
        int r = (t / SS_) % 3;
        int s = t % SS_;
        int ci = fps[b * SS_ + s];
        out[t] = xyz[((size_t)b * 3 + r) * NN_ + ci];
    }
}

extern "C" void kernel_launch(void* const* d_in, const int* in_sizes, int n_in,
                              void* d_out, int out_size, void* d_ws, size_t ws_size,
                              hipStream_t stream) {
    (void)in_sizes; (void)n_in; (void)out_size; (void)ws_size;
    const float* xyz = (const float*)d_in[0];
    const float* pts = (const float*)d_in[1];
    const int*   fps = (const int*)d_in[2];
    const float* W1 = (const float*)d_in[3];
    const float* g1 = (const float*)d_in[4];
    const float* b1 = (const float*)d_in[5];
    const float* W2 = (const float*)d_in[6];
    const float* g2 = (const float*)d_in[7];
    const float* b2 = (const float*)d_in[8];
    const float* W3 = (const float*)d_in[9];
    const float* g3 = (const float*)d_in[10];
    const float* b3 = (const float*)d_in[11];
    float* out = (float*)d_out;
    float* ws = (float*)d_ws;

    uint4* fbf = (uint4*)(ws + FBF_OFF);
    uint4* wpk = (uint4*)(ws + WPK_OFF);
    float* st  = ws + ST_OFF;
    float* gmm = ws + GMM_OFF;

    hipMemsetAsync(st, 0, 512 * sizeof(float), stream);   // zero stats before front's gram atomics
    k_front<<<4096 + 7, 256, 0, stream>>>(xyz, pts, fps, fbf, W1, W2, W3, wpk, st);
    k_p2<<<1024, 256, 0, stream>>>(fbf, wpk, st, W1, g1, b1);
    k_p3_fused<<<1024, 256, 0, stream>>>(fbf, wpk, st, W1, g1, b1, g2, b2, g3, gmm);
    k_outx<<<1024 + 192, 256, 0, stream>>>(gmm, st, g3, b3, xyz, fps, out);
}

// Round 8
// 233.657 us; speedup vs baseline: 1.8985x; 1.1382x over previous
//
#include <hip/hip_runtime.h>
#include <hip/hip_bf16.h>

#define BB_ 8
#define NN_ 8192
#define SS_ 2048
#define NS 32
#define C1 64
#define C2 64
#define C3 128
#define RAD2 0.04f
#define BN_EPS 1e-5f
#define M_TOT (BB_*SS_*NS)   // 524288
#define INV_M (1.0f/524288.0f)
#define YSTR 34              // LDS row stride (dwords): conflict-free frag reads

typedef __attribute__((ext_vector_type(8))) short bf16x8;
typedef __attribute__((ext_vector_type(4))) float f32x4;

// ws float offsets
#define FBF_OFF 0          // feat bf16 [M_TOT][8] = 2,097,152 floats (8 MB)
#define WPK_OFF 2097152    // packed weight frags: 1792 uint4
#define ST_OFF  2104320    // 512: gram[27] | sum2@64 sq2@128 | sum3@192 sq3@320
#define GMM_OFF 2104832    // float per (group, o3): 16384*128 = 2,097,152 floats (8 MB)

__device__ inline unsigned pkbf(float a, float b) {
    __hip_bfloat162 h = __float22bfloat162_rn(make_float2(a, b));
    unsigned r; __builtin_memcpy(&r, &h, 4); return r;
}
__device__ inline bf16x8 asfrag(uint4 v) { bf16x8 r; __builtin_memcpy(&r, &v, 16); return r; }
__device__ inline float bflo(unsigned u) { unsigned x = u << 16; float f; __builtin_memcpy(&f, &x, 4); return f; }
__device__ inline float bfhi(unsigned u) { unsigned x = u & 0xffff0000u; float f; __builtin_memcpy(&f, &x, 4); return f; }

__device__ inline void fin1_ch(const float* __restrict__ st, const float* __restrict__ W1,
                               const float* __restrict__ g, const float* __restrict__ bb,
                               int o, float* __restrict__ al, float* __restrict__ cl) {
    float w[6];
    #pragma unroll
    for (int i = 0; i < 6; ++i) w[i] = W1[o * 6 + i];
    float ms = 0.f;
    #pragma unroll
    for (int i = 0; i < 6; ++i) ms = fmaf(w[i], st[i], ms);
    float m = ms * INV_M;
    float e2 = 0.f;
    #pragma unroll
    for (int ci = 0; ci < 6; ++ci)
        #pragma unroll
        for (int d = 0; d < 6; ++d) {
            int lo = ci < d ? ci : d, hi = ci < d ? d : ci;
            int idx = 6 + lo * 6 - lo * (lo + 1) / 2 + hi;
            e2 = fmaf(w[ci] * w[d], st[idx], e2);
        }
    float var = e2 * INV_M - m * m;
    float ai = g[o] * (1.0f / sqrtf(var + BN_EPS));
    al[o] = ai;
    cl[o] = bb[o] - m * ai;
}

__device__ inline void fin_ch(const float* __restrict__ sum, const float* __restrict__ sq,
                              const float* __restrict__ g, const float* __restrict__ bb,
                              int o, float* __restrict__ al, float* __restrict__ cl) {
    float m = sum[o] * INV_M;
    float var = sq[o] * INV_M - m * m;
    float ai = g[o] * (1.0f / sqrtf(var + BN_EPS));
    al[o] = ai;
    cl[o] = bb[o] - m * ai;
}

// ---------------- front: blocks [0,4096) ball query (4-deep prefetch); [4096,4104) pack + stat zero ----------------
__global__ void k_front(const float* __restrict__ xyz, const float* __restrict__ pts,
                        const int* __restrict__ fps, uint4* __restrict__ fbf,
                        const float* __restrict__ W1, const float* __restrict__ W2,
                        const float* __restrict__ W3, uint4* __restrict__ wf,
                        float* __restrict__ st) {
    __shared__ int lidx[4][NS];
    int tid = threadIdx.x;
    if (blockIdx.x >= 4096) {                      // ---- pack path ----
        int bb = blockIdx.x - 4096;
        if (bb == 7) { st[tid] = 0.f; st[tid + 256] = 0.f; return; }
        int t = bb * 256 + tid;   // < 1792
        int l = t & 63, p = l & 15, qd = l >> 4;
        float v[8];
        if (t < 256) {
            int mt = t >> 6;
            #pragma unroll
            for (int j = 0; j < 8; ++j)
                v[j] = (qd == 0 && j < 6) ? W1[(mt * 16 + p) * 6 + j] : 0.f;   // A[m=o1][k=c]
        } else if (t < 768) {
            int fr = (t - 256) >> 6;
            int mt = fr >> 1, kf = fr & 1;
            #pragma unroll
            for (int j = 0; j < 8; ++j)
                v[j] = W2[(16 * mt + p) * 64 + kf * 32 + qd * 8 + j];          // A[m=o2][k=c]
        } else {
            int fr = (t - 768) >> 6;
            int nt = fr >> 1, kf = fr & 1;
            #pragma unroll
            for (int j = 0; j < 8; ++j)
                v[j] = W3[(nt * 16 + p) * 64 + kf * 32 + qd * 8 + j];          // B[k=c][n=o3]
        }
        uint4 o;
        o.x = pkbf(v[0], v[1]); o.y = pkbf(v[2], v[3]);
        o.z = pkbf(v[4], v[5]); o.w = pkbf(v[6], v[7]);
        wf[t] = o;
        return;
    }
    // ---- ball query: 4-deep prefetch pipeline (256 pts in flight), exit check per 256 pts ----
    int wave = (blockIdx.x * blockDim.x + tid) >> 6;
    int lane = tid & 63;
    int wslot = tid >> 6;
    int b = wave / SS_;
    const float* xb = xyz + (size_t)b * 3 * NN_;
    const float* pb = pts + (size_t)b * 3 * NN_;
    int ci = fps[wave];
    float cx = xb[ci], cy = xb[NN_ + ci], cz = xb[2 * NN_ + ci];

    float sx[4], sy[4], sz[4];
    #pragma unroll
    for (int k = 0; k < 4; ++k) {
        sx[k] = xb[k * 64 + lane];
        sy[k] = xb[NN_ + k * 64 + lane];
        sz[k] = xb[2 * NN_ + k * 64 + lane];
    }
    int found = 0;
    int first_i = -1;
    #pragma unroll 1
    for (int base = 0; base < NN_; base += 256) {
        #pragma unroll
        for (int k = 0; k < 4; ++k) {
            float xv = sx[k], yv = sy[k], zv = sz[k];
            int nb = base + 256 + k * 64;
            if (nb >= NN_) nb = 0;                 // wraparound prefetch (values unused)
            sx[k] = xb[nb + lane];
            sy[k] = xb[NN_ + nb + lane];
            sz[k] = xb[2 * NN_ + nb + lane];
            float dx = xv - cx, dy = yv - cy, dz = zv - cz;
            float d2 = __fadd_rn(__fadd_rn(__fmul_rn(dx, dx), __fmul_rn(dy, dy)), __fmul_rn(dz, dz));
            bool inr = d2 <= RAD2;
            unsigned long long mask = __ballot(inr);
            if (first_i < 0 && mask) first_i = base + k * 64 + __builtin_ctzll(mask);
            if (inr) {
                int pos = found + __popcll(mask & ((1ull << lane) - 1ull));
                if (pos < NS) lidx[wslot][pos] = base + k * 64 + lane;
            }
            found += __popcll(mask);
        }
        if (found >= NS) break;
    }
    if (found > NS) found = NS;
    if (lane < NS) {
        int j = (lane < found) ? lidx[wslot][lane] : first_i;
        uint4 o;
        o.x = pkbf(xb[j] - cx,           xb[NN_ + j] - cy);
        o.y = pkbf(xb[2 * NN_ + j] - cz, pb[j]);
        o.z = pkbf(pb[NN_ + j],          pb[2 * NN_ + j]);
        o.w = 0u;
        fbf[(size_t)wave * NS + lane] = o;
    }
}

// ---------------- P1: f-sums + 6x6 Gram over bf16 feat (1024 blocks: 16 waves/CU) ----------------
__global__ void k_p1(const uint4* __restrict__ fbf, float* __restrict__ st) {
    __shared__ float sacc[27];
    int tid = threadIdx.x;
    if (tid < 27) sacc[tid] = 0.f;
    __syncthreads();
    int gt = blockIdx.x * 256 + tid;   // 262144 threads
    float vals[27];
    #pragma unroll
    for (int i = 0; i < 27; ++i) vals[i] = 0.f;
    #pragma unroll 1
    for (int it = 0; it < M_TOT / 262144; ++it) {
        uint4 w = fbf[it * 262144 + gt];
        float f[6] = { bflo(w.x), bfhi(w.x), bflo(w.y), bfhi(w.y), bflo(w.z), bfhi(w.z) };
        #pragma unroll
        for (int c = 0; c < 6; ++c) vals[c] += f[c];
        int q = 6;
        #pragma unroll
        for (int c = 0; c < 6; ++c)
            #pragma unroll
            for (int d = c; d < 6; ++d) { vals[q] = fmaf(f[c], f[d], vals[q]); ++q; }
    }
    int lane = tid & 63;
    #pragma unroll
    for (int i = 0; i < 27; ++i) {
        float v = vals[i];
        #pragma unroll
        for (int d = 32; d; d >>= 1) v += __shfl_xor(v, d);
        if (lane == 0) atomicAdd(&sacc[i], v);
    }
    __syncthreads();
    if (tid < 27) atomicAdd(&st[tid], sacc[tid]);
}

// ---------------- P2: layers 1-2 stats pass. Barrier-free inner pipeline (R5-verified) ----------------
__global__ __launch_bounds__(256, 4) void k_p2(
        const uint4* __restrict__ fbf, const uint4* __restrict__ wpk,
        float* __restrict__ st,
        const float* __restrict__ W1, const float* __restrict__ g1, const float* __restrict__ b1) {
    __shared__ unsigned yls[4][64 * YSTR];
    __shared__ float bs[C2], bq[C2];
    __shared__ float a1ls[C1], c1ls[C1];
    int tid = threadIdx.x, wslot = tid >> 6, lane = tid & 63;
    int p = lane & 15, qd = lane >> 4;
    int tile0 = blockIdx.x * 8 + wslot;           // wave tiles: tile0, tile0+4
    uint4 bv[4];
    #pragma unroll
    for (int nt = 0; nt < 4; ++nt) {              // issue early: overlaps prologue
        uint4 v = make_uint4(0u, 0u, 0u, 0u);
        if (qd == 0) v = fbf[tile0 * 64 + nt * 16 + p];
        bv[nt] = v;
    }
    bf16x8 w1r[4];
    #pragma unroll
    for (int mt = 0; mt < 4; ++mt) w1r[mt] = asfrag(wpk[mt * 64 + lane]);   // hoisted L1 weights
    if (tid < C2) { bs[tid] = 0.f; bq[tid] = 0.f; fin1_ch(st, W1, g1, b1, tid, a1ls, c1ls); }
    __syncthreads();
    const uint4* w2f = wpk + 256;
    unsigned* my = yls[wslot];
    float s2[4][4], q2[4][4];
    #pragma unroll
    for (int i = 0; i < 4; ++i)
        #pragma unroll
        for (int r = 0; r < 4; ++r) { s2[i][r] = 0.f; q2[i][r] = 0.f; }

    #pragma unroll
    for (int t = 0; t < 2; ++t) {
        uint4 nbv[4];
        if (t == 0) {
            #pragma unroll
            for (int nt = 0; nt < 4; ++nt) {      // prefetch second tile
                uint4 v = make_uint4(0u, 0u, 0u, 0u);
                if (qd == 0) v = fbf[(tile0 + 4) * 64 + nt * 16 + p];
                nbv[nt] = v;
            }
        }
        bf16x8 B1[4];
        #pragma unroll
        for (int nt = 0; nt < 4; ++nt) B1[nt] = asfrag(bv[nt]);
        #pragma unroll
        for (int mt = 0; mt < 4; ++mt) {
            bf16x8 A = w1r[mt];
            float4 av = *(const float4*)(a1ls + mt * 16 + qd * 4);
            float4 cv = *(const float4*)(c1ls + mt * 16 + qd * 4);
            #pragma unroll
            for (int nt = 0; nt < 4; ++nt) {
                f32x4 acc = {0.f, 0.f, 0.f, 0.f};
                acc = __builtin_amdgcn_mfma_f32_16x16x32_bf16(A, B1[nt], acc, 0, 0, 0);
                float y0 = fmaxf(fmaf(av.x, acc[0], cv.x), 0.f);
                float y1 = fmaxf(fmaf(av.y, acc[1], cv.y), 0.f);
                float y2 = fmaxf(fmaf(av.z, acc[2], cv.z), 0.f);
                float y3 = fmaxf(fmaf(av.w, acc[3], cv.w), 0.f);
                int a = (nt * 16 + p) * YSTR + mt * 8 + qd * 2;
                *(uint2*)&my[a] = make_uint2(pkbf(y0, y1), pkbf(y2, y3));
            }
        }
        asm volatile("" ::: "memory");   // y1 writes -> B2 reads (wave-private LDS)
        bf16x8 B2[4][2];
        #pragma unroll
        for (int nt = 0; nt < 4; ++nt)
            #pragma unroll
            for (int kf = 0; kf < 2; ++kf)
                B2[nt][kf] = asfrag(*(const uint4*)&my[(nt * 16 + p) * YSTR + kf * 16 + qd * 4]);
        asm volatile("" ::: "memory");
        #pragma unroll
        for (int mt = 0; mt < 4; ++mt) {
            f32x4 acc[4];
            #pragma unroll
            for (int nt = 0; nt < 4; ++nt) acc[nt] = (f32x4){0.f, 0.f, 0.f, 0.f};
            #pragma unroll
            for (int kf = 0; kf < 2; ++kf) {
                bf16x8 W = asfrag(w2f[(mt * 2 + kf) * 64 + lane]);
                #pragma unroll
                for (int nt = 0; nt < 4; ++nt)
                    acc[nt] = __builtin_amdgcn_mfma_f32_16x16x32_bf16(W, B2[nt][kf], acc[nt], 0, 0, 0);
            }
            #pragma unroll
            for (int r = 0; r < 4; ++r) {
                float u0 = acc[0][r], u1 = acc[1][r], u2 = acc[2][r], u3 = acc[3][r];
                s2[mt][r] += (u0 + u1) + (u2 + u3);
                q2[mt][r] = fmaf(u0, u0, fmaf(u1, u1, fmaf(u2, u2, fmaf(u3, u3, q2[mt][r]))));
            }
        }
        if (t == 0) {
            #pragma unroll
            for (int nt = 0; nt < 4; ++nt) bv[nt] = nbv[nt];
        }
        asm volatile("" ::: "memory");   // LDS reuse before next tile's stage A
    }
    // stats reduce over p + block + global
    #pragma unroll
    for (int mt = 0; mt < 4; ++mt)
        #pragma unroll
        for (int r = 0; r < 4; ++r) {
            float s = s2[mt][r], q = q2[mt][r];
            #pragma unroll
            for (int off = 1; off <= 8; off <<= 1) { s += __shfl_xor(s, off); q += __shfl_xor(q, off); }
            if (p == 0) {
                atomicAdd(&bs[mt * 16 + qd * 4 + r], s);
                atomicAdd(&bq[mt * 16 + qd * 4 + r], q);
            }
        }
    __syncthreads();
    if (tid < C2) { atomicAdd(&st[64 + tid], bs[tid]); atomicAdd(&st[128 + tid], bq[tid]); }
}

// ---------------- P3: fused 3 layers from fbf + both-tile load hoist ----------------
__global__ __launch_bounds__(256, 4) void k_p3_fused(
        const uint4* __restrict__ fbf, const uint4* __restrict__ wpk,
        float* __restrict__ st,
        const float* __restrict__ W1, const float* __restrict__ g1, const float* __restrict__ b1,
        const float* __restrict__ g2, const float* __restrict__ b2,
        const float* __restrict__ g3, float* __restrict__ gmm) {
    __shared__ unsigned yls[4][64 * YSTR];
    __shared__ float bs[C3], bq[C3];
    __shared__ float a1ls[C1], c1ls[C1], a2ls[C2], c2ls[C2];
    int tid = threadIdx.x, wslot = tid >> 6, lane = tid & 63;
    int p = lane & 15, qd = lane >> 4;
    int tile0 = blockIdx.x * 4 + wslot;
    uint4 bv0[4], bv1[4];
    #pragma unroll
    for (int nt = 0; nt < 4; ++nt) {              // hoist BOTH tiles' loads: overlap prologue+barrier
        uint4 v0 = make_uint4(0u, 0u, 0u, 0u);
        uint4 v1 = make_uint4(0u, 0u, 0u, 0u);
        if (qd == 0) {
            v0 = fbf[tile0 * 64 + nt * 16 + p];
            v1 = fbf[(tile0 + 4096) * 64 + nt * 16 + p];
        }
        bv0[nt] = v0; bv1[nt] = v1;
    }
    unsigned posm = 0;
    #pragma unroll
    for (int i = 0; i < 8; ++i) posm |= (g3[i * 16 + p] >= 0.f) ? (1u << i) : 0u;
    if (tid < 128) bs[tid] = 0.f; else bq[tid - 128] = 0.f;
    if (tid < 64) fin1_ch(st, W1, g1, b1, tid, a1ls, c1ls);
    else if (tid < 128) fin_ch(st + 64, st + 128, g2, b2, tid - 64, a2ls, c2ls);
    __syncthreads();
    const uint4* w1f = wpk;
    const uint4* w2f = wpk + 256;
    const uint4* w3f = wpk + 768;
    unsigned* my = yls[wslot];

    #pragma unroll
    for (int it = 0; it < 2; ++it) {
        int tile = tile0 + it * 4096;
        // ---- L1 ----
        #pragma unroll
        for (int mt = 0; mt < 4; ++mt) {
            bf16x8 Aw = asfrag(w1f[mt * 64 + lane]);
            float4 av = *(const float4*)(a1ls + mt * 16 + qd * 4);
            float4 cv = *(const float4*)(c1ls + mt * 16 + qd * 4);
            #pragma unroll
            for (int nt = 0; nt < 4; ++nt) {
                uint4 bcur = (it == 0) ? bv0[nt] : bv1[nt];   // it is compile-time (unrolled)
                f32x4 acc = {0.f, 0.f, 0.f, 0.f};
                acc = __builtin_amdgcn_mfma_f32_16x16x32_bf16(Aw, asfrag(bcur), acc, 0, 0, 0);
                float y0 = fmaxf(fmaf(av.x, acc[0], cv.x), 0.f);
                float y1 = fmaxf(fmaf(av.y, acc[1], cv.y), 0.f);
                float y2 = fmaxf(fmaf(av.z, acc[2], cv.z), 0.f);
                float y3 = fmaxf(fmaf(av.w, acc[3], cv.w), 0.f);
                int a = (nt * 16 + p) * YSTR + mt * 8 + qd * 2;
                *(uint2*)&my[a] = make_uint2(pkbf(y0, y1), pkbf(y2, y3));
            }
        }
        asm volatile("" ::: "memory");   // y1 writes -> B2 reads (wave-private LDS)
        bf16x8 B2[4][2];
        #pragma unroll
        for (int nt = 0; nt < 4; ++nt)
            #pragma unroll
            for (int kf = 0; kf < 2; ++kf)
                B2[nt][kf] = asfrag(*(const uint4*)&my[(nt * 16 + p) * YSTR + kf * 16 + qd * 4]);
        asm volatile("" ::: "memory");
        // ---- L2 ----
        #pragma unroll
        for (int mt = 0; mt < 4; ++mt) {
            f32x4 acc[4];
            #pragma unroll
            for (int nt = 0; nt < 4; ++nt) acc[nt] = (f32x4){0.f, 0.f, 0.f, 0.f};
            #pragma unroll
            for (int kf = 0; kf < 2; ++kf) {
                bf16x8 W = asfrag(w2f[(mt * 2 + kf) * 64 + lane]);
                #pragma unroll
                for (int nt = 0; nt < 4; ++nt)
                    acc[nt] = __builtin_amdgcn_mfma_f32_16x16x32_bf16(W, B2[nt][kf], acc[nt], 0, 0, 0);
            }
            float4 av = *(const float4*)(a2ls + mt * 16 + qd * 4);
            float4 cv = *(const float4*)(c2ls + mt * 16 + qd * 4);
            #pragma unroll
            for (int nt = 0; nt < 4; ++nt) {
                float y0 = fmaxf(fmaf(av.x, acc[nt][0], cv.x), 0.f);
                float y1 = fmaxf(fmaf(av.y, acc[nt][1], cv.y), 0.f);
                float y2 = fmaxf(fmaf(av.z, acc[nt][2], cv.z), 0.f);
                float y3 = fmaxf(fmaf(av.w, acc[nt][3], cv.w), 0.f);
                int a = (nt * 16 + p) * YSTR + mt * 8 + qd * 2;
                *(uint2*)&my[a] = make_uint2(pkbf(y0, y1), pkbf(y2, y3));
            }
        }
        asm volatile("" ::: "memory");   // x2 writes -> A3 reads (wave-private LDS)
        bf16x8 A3[4][2];
        #pragma unroll
        for (int mt = 0; mt < 4; ++mt) {
            A3[mt][0] = asfrag(*(const uint4*)&my[(mt * 16 + p) * YSTR + qd * 4]);
            A3[mt][1] = asfrag(*(const uint4*)&my[(mt * 16 + p) * YSTR + 16 + qd * 4]);
        }
        asm volatile("" ::: "memory");
        // ---- L3: runtime nt loop, W-frag 1-deep double buffer ----
        uint4 wva = w3f[lane];
        uint4 wvb = w3f[64 + lane];
        #pragma unroll 1
        for (int nt = 0; nt < 8; ++nt) {
            int nn = (nt < 7) ? nt + 1 : 7;
            uint4 nwa = w3f[(nn * 2 + 0) * 64 + lane];   // prefetch next W pair
            uint4 nwb = w3f[(nn * 2 + 1) * 64 + lane];
            bf16x8 Wa = asfrag(wva), Wb = asfrag(wvb);
            f32x4 acc[4];
            #pragma unroll
            for (int mt = 0; mt < 4; ++mt) {
                acc[mt] = __builtin_amdgcn_mfma_f32_16x16x32_bf16(A3[mt][0], Wa,
                            (f32x4){0.f, 0.f, 0.f, 0.f}, 0, 0, 0);
                acc[mt] = __builtin_amdgcn_mfma_f32_16x16x32_bf16(A3[mt][1], Wb, acc[mt], 0, 0, 0);
            }
            bool pn = (posm >> nt) & 1;
            float s = 0.f, q = 0.f, va = 0.f, vb = 0.f;
            #pragma unroll
            for (int mt = 0; mt < 4; ++mt) {
                float v0 = acc[mt][0], v1 = acc[mt][1], v2 = acc[mt][2], v3 = acc[mt][3];
                s += (v0 + v1) + (v2 + v3);
                q = fmaf(v0, v0, fmaf(v1, v1, fmaf(v2, v2, fmaf(v3, v3, q))));
                float mx = fmaxf(fmaxf(v0, v1), fmaxf(v2, v3));
                float mn = fminf(fminf(v0, v1), fminf(v2, v3));
                float vv = pn ? mx : -mn;
                if (mt == 0) va = vv;
                else if (mt == 1) va = fmaxf(va, vv);
                else if (mt == 2) vb = vv;
                else vb = fmaxf(vb, vv);
            }
            s += __shfl_xor(s, 16); s += __shfl_xor(s, 32);
            q += __shfl_xor(q, 16); q += __shfl_xor(q, 32);
            va = fmaxf(va, __shfl_xor(va, 16)); va = fmaxf(va, __shfl_xor(va, 32));
            vb = fmaxf(vb, __shfl_xor(vb, 16)); vb = fmaxf(vb, __shfl_xor(vb, 32));
            if (lane < 16) {
                gmm[(size_t)(tile * 2 + 0) * C3 + nt * 16 + lane] = va;
                gmm[(size_t)(tile * 2 + 1) * C3 + nt * 16 + lane] = vb;
                atomicAdd(&bs[nt * 16 + lane], s);
                atomicAdd(&bq[nt * 16 + lane], q);
            }
            wva = nwa; wvb = nwb;
        }
    }
    __syncthreads();
    if (tid < C3) { atomicAdd(&st[192 + tid], bs[tid]); atomicAdd(&st[320 + tid], bq[tid]); }
}

// ---------------- epilogue: fin3 inlined; coalesced gmm read; out + xyz ----------------
__global__ void k_outx(const float* __restrict__ gmm, const float* __restrict__ st,
                       const float* __restrict__ g3, const float* __restrict__ b3,
                       const float* __restrict__ xyz, const int* __restrict__ fps,
                       float* __restrict__ out) {
    __shared__ float T[C3][17];
    __shared__ float a3ls[C3], c3ls[C3];
    int blk = blockIdx.x, tid = threadIdx.x;
    if (blk < 1024) {
        if (tid < C3) fin_ch(st + 192, st + 320, g3, b3, tid, a3ls, c3ls);
        __syncthreads();
        int b = blk >> 7, s0 = (blk & 127) << 4;
        #pragma unroll
        for (int i = 0; i < 8; ++i) {
            int idx = i * 256 + tid;
            int sl = idx >> 7, o = idx & 127;
            float m = gmm[((size_t)(b * SS_ + s0 + sl)) * C3 + o];
            float a = a3ls[o];
            float v = (a >= 0.f) ? m : -m;
            T[o][sl] = fmaxf(fmaf(a, v, c3ls[o]), 0.f);
        }
        __syncthreads();
        int o = tid & 127, sh = tid >> 7;
        float* dst = out + (size_t)BB_ * 3 * SS_ + ((size_t)b * C3 + o) * SS_ + s0 + sh * 8;
        float4 w0, w1;
        w0.x = T[o][sh * 8 + 0]; w0.y = T[o][sh * 8 + 1];
        w0.z = T[o][sh * 8 + 2]; w0.w = T[o][sh * 8 + 3];
        w1.x = T[o][sh * 8 + 4]; w1.y = T[o][sh * 8 + 5];
        w1.z = T[o][sh * 8 + 6]; w1.w = T[o][sh * 8 + 7];
        *(float4*)dst = w0; *(float4*)(dst + 4) = w1;
    } else {
        int t = (blk - 1024) * 256 + tid;   // < 49152
        int b = t / (3 * SS_);
        int r = (t / SS_) % 3;
        int s = t % SS_;
        int ci = fps[b * SS_ + s];
        out[t] = xyz[((size_t)b * 3 + r) * NN_ + ci];
    }
}

extern "C" void kernel_launch(void* const* d_in, const int* in_sizes, int n_in,
                              void* d_out, int out_size, void* d_ws, size_t ws_size,
                              hipStream_t stream) {
    (void)in_sizes; (void)n_in; (void)out_size; (void)ws_size;
    const float* xyz = (const float*)d_in[0];
    const float* pts = (const float*)d_in[1];
    const int*   fps = (const int*)d_in[2];
    const float* W1 = (const float*)d_in[3];
    const float* g1 = (const float*)d_in[4];
    const float* b1 = (const float*)d_in[5];
    const float* W2 = (const float*)d_in[6];
    const float* g2 = (const float*)d_in[7];
    const float* b2 = (const float*)d_in[8];
    const float* W3 = (const float*)d_in[9];
    const float* g3 = (const float*)d_in[10];
    const float* b3 = (const float*)d_in[11];
    float* out = (float*)d_out;
    float* ws = (float*)d_ws;

    uint4* fbf = (uint4*)(ws + FBF_OFF);
    uint4* wpk = (uint4*)(ws + WPK_OFF);
    float* st  = ws + ST_OFF;
    float* gmm = ws + GMM_OFF;

    k_front<<<4096 + 8, 256, 0, stream>>>(xyz, pts, fps, fbf, W1, W2, W3, wpk, st);
    k_p1<<<1024, 256, 0, stream>>>(fbf, st);
    k_p2<<<1024, 256, 0, stream>>>(fbf, wpk, st, W1, g1, b1);
    k_p3_fused<<<1024, 256, 0, stream>>>(fbf, wpk, st, W1, g1, b1, g2, b2, g3, gmm);
    k_outx<<<1024 + 192, 256, 0, stream>>>(gmm, st, g3, b3, xyz, fps, out);
}